// Round 4
// baseline (216.122 us; speedup 1.0000x reference)
//
#include <hip/hip_runtime.h>

// Problem constants (from reference)
#define NUM_TOKENS   16384
#define NUM_HEADS    8
#define HEAD_SIZE    128
#define NUM_BLOCKS   4096
#define BLOCK_SIZE_  16
#define SLOT_ELEMS   (NUM_HEADS * HEAD_SIZE)          // 1024 floats per slot
#define SLOT_VEC4    (SLOT_ELEMS / 4)                 // 256 float4 per slot
#define NUM_SLOTS    (NUM_BLOCKS * BLOCK_SIZE_)       // 65536
#define CACHE_ELEMS  ((long)NUM_SLOTS * SLOT_ELEMS)   // 67,108,864 floats per cache

// Blocks per half-grid (K half / V half). 1024 blocks x 256 thr = 4096 waves
// per half; 8192 waves total = exactly the device wave capacity (256 CU x 32).
#define HALF_BLOCKS  1024

// inv[slot] = token index writing that slot, or -1. Slots are unique, so the
// scatter is race-free. (inv is pre-filled with -1 via hipMemsetAsync 0xFF.)
__global__ void build_inverse_kernel(const int* __restrict__ slot_mapping,
                                     int* __restrict__ inv) {
    int t = blockIdx.x * blockDim.x + threadIdx.x;
    if (t < NUM_TOKENS) {
        int s = slot_mapping[t];
        if (s >= 0) inv[s] = t;
    }
}

// Wave-per-slot, stream-split fused kernel.
//  - blockIdx.x < HALF_BLOCKS  : process the K cache (read key/kc, write ok)
//  - blockIdx.x >= HALF_BLOCKS : process the V cache (read value/vc, write ov)
// Each wave owns whole slots (64 lanes x 4 float4 = 4 KB); per slot it issues
// 4 independent 16B loads then 4 stores (unrolled -> 4-deep outstanding
// loads/thread). Branch token>=0 is wave-uniform (scalar via readfirstlane).
__global__ void fused_cache_kernel(const float4* __restrict__ key,
                                   const float4* __restrict__ value,
                                   const float4* __restrict__ kc,
                                   const float4* __restrict__ vc,
                                   const int* __restrict__ inv,
                                   float4* __restrict__ ok,
                                   float4* __restrict__ ov) {
    bool is_v = blockIdx.x >= HALF_BLOCKS;
    const float4* __restrict__ src_tok   = is_v ? value : key;
    const float4* __restrict__ src_cache = is_v ? vc    : kc;
    float4* __restrict__       dst       = is_v ? ov    : ok;

    int halfBlk = blockIdx.x - (is_v ? HALF_BLOCKS : 0);
    int gw   = (halfBlk * blockDim.x + threadIdx.x) >> 6;   // wave id in half
    int lane = threadIdx.x & 63;
    const int NW = HALF_BLOCKS * 256 / 64;                  // waves per half

    for (int slot = gw; slot < NUM_SLOTS; slot += NW) {
        int token = __builtin_amdgcn_readfirstlane(inv[slot]);
        long db = ((long)slot << 8) + lane;                 // dst base (float4)
        if (token >= 0) {
            long sb = ((long)token << 8) + lane;
            float4 r0 = src_tok[sb +   0];
            float4 r1 = src_tok[sb +  64];
            float4 r2 = src_tok[sb + 128];
            float4 r3 = src_tok[sb + 192];
            dst[db +   0] = r0;
            dst[db +  64] = r1;
            dst[db + 128] = r2;
            dst[db + 192] = r3;
        } else {
            float4 r0 = src_cache[db +   0];
            float4 r1 = src_cache[db +  64];
            float4 r2 = src_cache[db + 128];
            float4 r3 = src_cache[db + 192];
            dst[db +   0] = r0;
            dst[db +  64] = r1;
            dst[db + 128] = r2;
            dst[db + 192] = r3;
        }
    }
}

// --- Fallback two-pass path (if ws too small) -------------------------------

__global__ void copy_cache_kernel(const float4* __restrict__ kc,
                                  const float4* __restrict__ vc,
                                  float4* __restrict__ ok,
                                  float4* __restrict__ ov,
                                  long n4) {
    long i = (long)blockIdx.x * blockDim.x + threadIdx.x;
    long stride = (long)gridDim.x * blockDim.x;
    for (; i < n4; i += stride) {
        ok[i] = kc[i];
        ov[i] = vc[i];
    }
}

__global__ void scatter_kv_kernel(const float4* __restrict__ key,
                                  const float4* __restrict__ value,
                                  const int* __restrict__ slot_mapping,
                                  float4* __restrict__ ok,
                                  float4* __restrict__ ov) {
    int token = blockIdx.x;
    int slot = slot_mapping[token];
    if (slot < 0) return;
    int tid = threadIdx.x;
    long src = (long)token * SLOT_VEC4 + tid;
    long dst = (long)slot  * SLOT_VEC4 + tid;
    ok[dst] = key[src];
    ov[dst] = value[src];
}

extern "C" void kernel_launch(void* const* d_in, const int* in_sizes, int n_in,
                              void* d_out, int out_size, void* d_ws, size_t ws_size,
                              hipStream_t stream) {
    const float* key   = (const float*)d_in[0];
    const float* value = (const float*)d_in[1];
    const float* kc    = (const float*)d_in[2];
    const float* vc    = (const float*)d_in[3];
    const int*   slots = (const int*)d_in[4];   // int32 on device (harness contract)
    // d_in[5], d_in[6] = k_scale, v_scale — unused (kv_cache_dtype='auto')

    float* ok = (float*)d_out;
    float* ov = ok + CACHE_ELEMS;

    if (ws_size >= (size_t)NUM_SLOTS * sizeof(int)) {
        int* inv = (int*)d_ws;
        hipMemsetAsync(inv, 0xFF, NUM_SLOTS * sizeof(int), stream);
        build_inverse_kernel<<<(NUM_TOKENS + 255) / 256, 256, 0, stream>>>(slots, inv);
        fused_cache_kernel<<<2 * HALF_BLOCKS, 256, 0, stream>>>(
            (const float4*)key, (const float4*)value,
            (const float4*)kc, (const float4*)vc, inv,
            (float4*)ok, (float4*)ov);
    } else {
        long n4 = CACHE_ELEMS / 4;
        copy_cache_kernel<<<2048, 256, 0, stream>>>(
            (const float4*)kc, (const float4*)vc, (float4*)ok, (float4*)ov, n4);
        scatter_kv_kernel<<<NUM_TOKENS, 256, 0, stream>>>(
            (const float4*)key, (const float4*)value, slots, (float4*)ok, (float4*)ov);
    }
}

// Round 5
// 215.138 us; speedup vs baseline: 1.0046x; 1.0046x over previous
//
#include <hip/hip_runtime.h>

// Problem constants (from reference)
#define NUM_TOKENS   16384
#define NUM_HEADS    8
#define HEAD_SIZE    128
#define NUM_BLOCKS   4096
#define BLOCK_SIZE_  16
#define SLOT_ELEMS   (NUM_HEADS * HEAD_SIZE)          // 1024 floats per slot
#define SLOT_VEC4    (SLOT_ELEMS / 4)                 // 256 float4 per slot
#define NUM_SLOTS    (NUM_BLOCKS * BLOCK_SIZE_)       // 65536
#define CACHE_ELEMS  ((long)NUM_SLOTS * SLOT_ELEMS)   // 67,108,864 floats per cache

// Grid: 2048 blocks x 256 threads = 8192 waves (device wave capacity).
// Low half handles the K cache, high half the V cache.
#define HALF_BLOCKS     1024
#define WAVES_PER_HALF  (HALF_BLOCKS * 256 / 64)      // 4096
#define SLOTS_PER_WAVE  (NUM_SLOTS / WAVES_PER_HALF)  // 16

// inv[slot] = token index writing that slot, or -1. Slots are unique, so the
// scatter is race-free. (inv is pre-filled with -1 via hipMemsetAsync 0xFF.)
__global__ void build_inverse_kernel(const int* __restrict__ slot_mapping,
                                     int* __restrict__ inv) {
    int t = blockIdx.x * blockDim.x + threadIdx.x;
    if (t < NUM_TOKENS) {
        int s = slot_mapping[t];
        if (s >= 0) inv[s] = t;
    }
}

// Wave-per-slot, stream-split, BRANCHLESS fused kernel.
// Each wave owns 16 slots of one cache. All 16 inv values are preloaded
// (independent loads), then each slot's source pointer is chosen with a
// cndmask select — no scalar branch, so payload loads pipeline freely.
__global__ __launch_bounds__(256)
void fused_cache_kernel(const float4* __restrict__ key,
                        const float4* __restrict__ value,
                        const float4* __restrict__ kc,
                        const float4* __restrict__ vc,
                        const int* __restrict__ inv,
                        float4* __restrict__ ok,
                        float4* __restrict__ ov) {
    bool is_v = blockIdx.x >= HALF_BLOCKS;
    const float4* __restrict__ src_tok   = is_v ? value : key;
    const float4* __restrict__ src_cache = is_v ? vc    : kc;
    float4* __restrict__       dst       = is_v ? ov    : ok;

    int halfBlk = is_v ? (blockIdx.x - HALF_BLOCKS) : blockIdx.x;
    int gw   = (halfBlk * 256 + (int)threadIdx.x) >> 6;   // wave id in half
    int lane = threadIdx.x & 63;

    // Phase 1: preload inv for all 16 slots (independent, all in flight).
    int tok[SLOTS_PER_WAVE];
#pragma unroll
    for (int k = 0; k < SLOTS_PER_WAVE; ++k)
        tok[k] = inv[gw + k * WAVES_PER_HALF];

    // Phase 2: payload. Branchless source select; unroll 4 -> 16 outstanding
    // 16B loads per thread without register pressure blow-up.
#pragma unroll 4
    for (int k = 0; k < SLOTS_PER_WAVE; ++k) {
        int  slot = gw + k * WAVES_PER_HALF;
        long db   = ((long)slot << 8) + lane;             // dst base (float4)
        const float4* __restrict__ src =
            (tok[k] >= 0) ? (src_tok + (((long)tok[k] << 8) + lane))
                          : (src_cache + db);
        float4 r0 = src[0];
        float4 r1 = src[64];
        float4 r2 = src[128];
        float4 r3 = src[192];
        dst[db +   0] = r0;
        dst[db +  64] = r1;
        dst[db + 128] = r2;
        dst[db + 192] = r3;
    }
}

// --- Fallback two-pass path (if ws too small) -------------------------------

__global__ void copy_cache_kernel(const float4* __restrict__ kc,
                                  const float4* __restrict__ vc,
                                  float4* __restrict__ ok,
                                  float4* __restrict__ ov,
                                  long n4) {
    long i = (long)blockIdx.x * blockDim.x + threadIdx.x;
    long stride = (long)gridDim.x * blockDim.x;
    for (; i < n4; i += stride) {
        ok[i] = kc[i];
        ov[i] = vc[i];
    }
}

__global__ void scatter_kv_kernel(const float4* __restrict__ key,
                                  const float4* __restrict__ value,
                                  const int* __restrict__ slot_mapping,
                                  float4* __restrict__ ok,
                                  float4* __restrict__ ov) {
    int token = blockIdx.x;
    int slot = slot_mapping[token];
    if (slot < 0) return;
    int tid = threadIdx.x;
    long src = (long)token * SLOT_VEC4 + tid;
    long dst = (long)slot  * SLOT_VEC4 + tid;
    ok[dst] = key[src];
    ov[dst] = value[src];
}

extern "C" void kernel_launch(void* const* d_in, const int* in_sizes, int n_in,
                              void* d_out, int out_size, void* d_ws, size_t ws_size,
                              hipStream_t stream) {
    const float* key   = (const float*)d_in[0];
    const float* value = (const float*)d_in[1];
    const float* kc    = (const float*)d_in[2];
    const float* vc    = (const float*)d_in[3];
    const int*   slots = (const int*)d_in[4];   // int32 on device (harness contract)
    // d_in[5], d_in[6] = k_scale, v_scale — unused (kv_cache_dtype='auto')

    float* ok = (float*)d_out;
    float* ov = ok + CACHE_ELEMS;

    if (ws_size >= (size_t)NUM_SLOTS * sizeof(int)) {
        int* inv = (int*)d_ws;
        hipMemsetAsync(inv, 0xFF, NUM_SLOTS * sizeof(int), stream);
        build_inverse_kernel<<<(NUM_TOKENS + 255) / 256, 256, 0, stream>>>(slots, inv);
        fused_cache_kernel<<<2 * HALF_BLOCKS, 256, 0, stream>>>(
            (const float4*)key, (const float4*)value,
            (const float4*)kc, (const float4*)vc, inv,
            (float4*)ok, (float4*)ov);
    } else {
        long n4 = CACHE_ELEMS / 4;
        copy_cache_kernel<<<2048, 256, 0, stream>>>(
            (const float4*)kc, (const float4*)vc, (float4*)ok, (float4*)ov, n4);
        scatter_kv_kernel<<<NUM_TOKENS, 256, 0, stream>>>(
            (const float4*)key, (const float4*)value, slots, (float4*)ok, (float4*)ov);
    }
}

// Round 6
// 199.517 us; speedup vs baseline: 1.0832x; 1.0783x over previous
//
#include <hip/hip_runtime.h>

// Problem constants (from reference)
#define NUM_TOKENS   16384
#define NUM_HEADS    8
#define HEAD_SIZE    128
#define NUM_BLOCKS   4096
#define BLOCK_SIZE_  16
#define SLOT_ELEMS   (NUM_HEADS * HEAD_SIZE)          // 1024 floats per slot
#define SLOT_VEC4    (SLOT_ELEMS / 4)                 // 256 float4 per slot
#define NUM_SLOTS    (NUM_BLOCKS * BLOCK_SIZE_)       // 65536
#define CACHE_ELEMS  ((long)NUM_SLOTS * SLOT_ELEMS)   // 67,108,864 floats per cache

// Non-temporal 16B load/store helpers (streaming data, zero reuse — bypass L2
// churn). clang builtins need ext_vector_type, not HIP's float4 struct.
typedef float f4_t __attribute__((ext_vector_type(4)));
__device__ __forceinline__ void nt_store(float4* p, float4 v) {
    __builtin_nontemporal_store(*(f4_t*)&v, (f4_t*)p);
}
__device__ __forceinline__ float4 nt_load(const float4* p) {
    f4_t v = __builtin_nontemporal_load((const f4_t*)p);
    return *(float4*)&v;
}

// inv[slot] = token index writing that slot, or -1. Slots are unique, so the
// scatter is race-free. (inv is pre-filled with -1 via hipMemsetAsync 0xFF.)
__global__ void build_inverse_kernel(const int* __restrict__ slot_mapping,
                                     int* __restrict__ inv) {
    int t = blockIdx.x * blockDim.x + threadIdx.x;
    if (t < NUM_TOKENS) {
        int s = slot_mapping[t];
        if (s >= 0) inv[s] = t;
    }
}

// Kernel A: token scatter. One block per token; thread moves one float4 of K
// and one of V. Sequential token reads, contiguous-4KB scattered writes.
// Needs no inv (slot_mapping is direct). ILP=2 per thread.
__global__ __launch_bounds__(256)
void scatter_kv_kernel(const float4* __restrict__ key,
                       const float4* __restrict__ value,
                       const int* __restrict__ slot_mapping,
                       float4* __restrict__ ok,
                       float4* __restrict__ ov) {
    int token = blockIdx.x;
    int slot = slot_mapping[token];   // one broadcast transaction per block
    if (slot < 0) return;             // dropped token
    int tid = threadIdx.x;            // 0..255
    long src = (long)token * SLOT_VEC4 + tid;
    long dst = (long)slot  * SLOT_VEC4 + tid;
    float4 rk = nt_load(key + src);
    float4 rv = nt_load(value + src);
    nt_store(ok + dst, rk);
    nt_store(ov + dst, rv);
}

// Kernel B: copy the holes. One block per slot; wave-uniform early exit if
// the slot is overwritten by a token (kernel A handles it). Otherwise pure
// streaming copy of 4KB from each input cache to the output. Dense moving
// window across the whole cache (blocks dispatch roughly in order).
__global__ __launch_bounds__(256)
void copy_holes_kernel(const float4* __restrict__ kc,
                       const float4* __restrict__ vc,
                       const int* __restrict__ inv,
                       float4* __restrict__ ok,
                       float4* __restrict__ ov) {
    int slot = blockIdx.x;
    if (inv[slot] >= 0) return;       // overwritten: scatter kernel owns it
    long i = (long)slot * SLOT_VEC4 + threadIdx.x;
    float4 rk = nt_load(kc + i);
    float4 rv = nt_load(vc + i);
    nt_store(ok + i, rk);
    nt_store(ov + i, rv);
}

// --- Fallback two-pass path (if ws too small) -------------------------------

__global__ void copy_cache_kernel(const float4* __restrict__ kc,
                                  const float4* __restrict__ vc,
                                  float4* __restrict__ ok,
                                  float4* __restrict__ ov,
                                  long n4) {
    long i = (long)blockIdx.x * blockDim.x + threadIdx.x;
    long stride = (long)gridDim.x * blockDim.x;
    for (; i < n4; i += stride) {
        ok[i] = kc[i];
        ov[i] = vc[i];
    }
}

extern "C" void kernel_launch(void* const* d_in, const int* in_sizes, int n_in,
                              void* d_out, int out_size, void* d_ws, size_t ws_size,
                              hipStream_t stream) {
    const float* key   = (const float*)d_in[0];
    const float* value = (const float*)d_in[1];
    const float* kc    = (const float*)d_in[2];
    const float* vc    = (const float*)d_in[3];
    const int*   slots = (const int*)d_in[4];   // int32 on device (harness contract)
    // d_in[5], d_in[6] = k_scale, v_scale — unused (kv_cache_dtype='auto')

    float* ok = (float*)d_out;
    float* ov = ok + CACHE_ELEMS;

    if (ws_size >= (size_t)NUM_SLOTS * sizeof(int)) {
        int* inv = (int*)d_ws;
        hipMemsetAsync(inv, 0xFF, NUM_SLOTS * sizeof(int), stream);
        build_inverse_kernel<<<(NUM_TOKENS + 255) / 256, 256, 0, stream>>>(slots, inv);
        copy_holes_kernel<<<NUM_SLOTS, 256, 0, stream>>>(
            (const float4*)kc, (const float4*)vc, inv, (float4*)ok, (float4*)ov);
        scatter_kv_kernel<<<NUM_TOKENS, 256, 0, stream>>>(
            (const float4*)key, (const float4*)value, slots, (float4*)ok, (float4*)ov);
    } else {
        long n4 = CACHE_ELEMS / 4;
        copy_cache_kernel<<<2048, 256, 0, stream>>>(
            (const float4*)kc, (const float4*)vc, (float4*)ok, (float4*)ov, n4);
        scatter_kv_kernel<<<NUM_TOKENS, 256, 0, stream>>>(
            (const float4*)key, (const float4*)value, slots, (float4*)ok, (float4*)ov);
    }
}